// Round 1
// baseline (268.237 us; speedup 1.0000x reference)
//
#include <hip/hip_runtime.h>
#include <hip/hip_bf16.h>

#define EPS 1e-8f

// Pass 1: per-edge score -> sigmoid -> store w, atomic row_sum[src] += w
__global__ void edge_w_kernel(const int* __restrict__ src,
                              const int* __restrict__ dst,
                              const float* __restrict__ emb1,
                              const float* __restrict__ emb2,
                              float* __restrict__ w,
                              float* __restrict__ row_sum,
                              int n_edges) {
    int e = blockIdx.x * blockDim.x + threadIdx.x;
    if (e >= n_edges) return;

    int s = src[e];
    int d = dst[e];

    const float4* a = (const float4*)(emb1 + (size_t)s * 16);
    const float4* b = (const float4*)(emb2 + (size_t)d * 16);

    float4 a0 = a[0], a1 = a[1], a2 = a[2], a3 = a[3];
    float4 b0 = b[0], b1 = b[1], b2 = b[2], b3 = b[3];

    float score = a0.x * b0.x + a0.y * b0.y + a0.z * b0.z + a0.w * b0.w
                + a1.x * b1.x + a1.y * b1.y + a1.z * b1.z + a1.w * b1.w
                + a2.x * b2.x + a2.y * b2.y + a2.z * b2.z + a2.w * b2.w
                + a3.x * b3.x + a3.y * b3.y + a3.z * b3.z + a3.w * b3.w;

    float wv = 1.0f / (1.0f + __expf(-score));

    w[e] = wv;
    atomicAdd(&row_sum[s], wv);
}

// Pass 2: normalize
__global__ void edge_norm_kernel(const int* __restrict__ src,
                                 const float* __restrict__ w,
                                 const float* __restrict__ row_sum,
                                 float* __restrict__ out,
                                 int n_edges) {
    int e = blockIdx.x * blockDim.x + threadIdx.x;
    if (e >= n_edges) return;
    int s = src[e];
    out[e] = w[e] / (row_sum[s] + EPS);
}

extern "C" void kernel_launch(void* const* d_in, const int* in_sizes, int n_in,
                              void* d_out, int out_size, void* d_ws, size_t ws_size,
                              hipStream_t stream) {
    const int*   src  = (const int*)d_in[0];
    const int*   dst  = (const int*)d_in[1];
    const float* emb1 = (const float*)d_in[2];
    const float* emb2 = (const float*)d_in[3];
    float* out = (float*)d_out;

    int n_edges = in_sizes[0];
    int n_nodes = in_sizes[2] / 16;

    // workspace layout: [row_sum: n_nodes floats][w: n_edges floats]
    float* row_sum = (float*)d_ws;
    float* w       = row_sum + n_nodes;

    hipMemsetAsync(row_sum, 0, (size_t)n_nodes * sizeof(float), stream);

    int block = 256;
    int grid1 = (n_edges + block - 1) / block;
    edge_w_kernel<<<grid1, block, 0, stream>>>(src, dst, emb1, emb2, w, row_sum, n_edges);
    edge_norm_kernel<<<grid1, block, 0, stream>>>(src, w, row_sum, out, n_edges);
}